// Round 4
// baseline (3299.268 us; speedup 1.0000x reference)
//
#include <hip/hip_runtime.h>
#include <hip/hip_bf16.h>

#define N_NODES 50000
#define FEAT    128
#define FP_LEN  2048
#define RADIUS  4
#define N_EDGES 600000
#define BN_EPS  1e-5f

typedef __attribute__((ext_vector_type(8))) short bh8;   // 8 bf16 = 4 VGPR
typedef __attribute__((ext_vector_type(4))) float f32x4;

// round-to-nearest-even fp32 -> bf16 (returns low 16 bits)
__device__ __forceinline__ unsigned bf16_rne(float x) {
    unsigned u = __float_as_uint(x);
    return (u + 0x7fffu + ((u >> 16) & 1u)) >> 16;
}

// split two floats into packed-pair hi/lo bf16 dwords (elem0 = low half)
__device__ __forceinline__ void split2(float x0, float x1, unsigned& hi, unsigned& lo) {
    unsigned h0 = bf16_rne(x0), h1 = bf16_rne(x1);
    float r0 = x0 - __uint_as_float(h0 << 16);
    float r1 = x1 - __uint_as_float(h1 << 16);
    hi = h0 | (h1 << 16);
    lo = bf16_rne(r0) | (bf16_rne(r1) << 16);
}

// Stage X[row0..row0+ROWS) x 128 fp32 -> LDS split bf16 hi/lo, XOR-swizzled
// (byte ^= (row&7)<<4 within each 256B row) for conflict-free b128 frag reads.
template <int ROWS, int NT>
__device__ __forceinline__ void stage_split(const float* __restrict__ X, int row0,
                                            unsigned short* Ahi, unsigned short* Alo,
                                            int t) {
    const int NF4 = ROWS * 32;  // float4 count
    const float4* X4 = (const float4*)(X + (size_t)row0 * FEAT);
    #pragma unroll
    for (int f = t; f < NF4; f += NT) {
        int row = f >> 5, kq = f & 31;  // k = kq*4
        float4 v = make_float4(0.f, 0.f, 0.f, 0.f);
        if (row0 + row < N_NODES) v = X4[f];
        unsigned h0, l0, h1, l1;
        split2(v.x, v.y, h0, l0);
        split2(v.z, v.w, h1, l1);
        int boff = (kq * 8) ^ ((row & 7) << 4);
        unsigned* dh = (unsigned*)((char*)Ahi + row * 256 + boff);
        unsigned* dl = (unsigned*)((char*)Alo + row * 256 + boff);
        dh[0] = h0; dh[1] = h1;
        dl[0] = l0; dl[1] = l1;
    }
}

// ---------------------------------------------------------------------------
// Zero accumulators.
// ---------------------------------------------------------------------------
__global__ __launch_bounds__(256) void k_zero(float* fp, float* stats,
                                              int* counts, int* cursor) {
    int i = blockIdx.x * blockDim.x + threadIdx.x;
    int n = gridDim.x * blockDim.x;
    for (int j = i; j < FP_LEN; j += n) fp[j] = 0.f;
    for (int j = i; j < RADIUS * 2 * FEAT; j += n) stats[j] = 0.f;
    for (int j = i; j < N_NODES; j += n) { counts[j] = 0; cursor[j] = 0; }
}

// ---------------------------------------------------------------------------
// W split+transpose: fp32 [128][N] -> hi/lo bf16 [N][128] (K-contiguous).
// y<5: init_w / soft_w (N=2048, 32 col-tiles); y>=5: hash_w (N=128, 2 tiles).
// ---------------------------------------------------------------------------
__global__ __launch_bounds__(256) void k_wsplit(
    const float* __restrict__ init_w, const float* __restrict__ soft_w,
    const float* __restrict__ hash_w,
    unsigned* __restrict__ WhiB, unsigned* __restrict__ WloB,
    unsigned* __restrict__ WhiH, unsigned* __restrict__ WloH) {
    __shared__ float Tl[128][65];
    int t = threadIdx.x;
    int y = blockIdx.y;
    const float* W;
    unsigned *Oh, *Ol;
    int N;
    if (y < 5) {
        N = FP_LEN;
        W = (y == 0) ? init_w : soft_w + (size_t)(y - 1) * FEAT * FP_LEN;
        Oh = WhiB + (size_t)y * FP_LEN * (FEAT / 2);
        Ol = WloB + (size_t)y * FP_LEN * (FEAT / 2);
    } else {
        if (blockIdx.x >= 2) return;  // uniform per block
        N = FEAT;
        W = hash_w + (size_t)(y - 5) * FEAT * FEAT;
        Oh = WhiH + (size_t)(y - 5) * FEAT * (FEAT / 2);
        Ol = WloH + (size_t)(y - 5) * FEAT * (FEAT / 2);
    }
    int n0 = blockIdx.x * 64;
    #pragma unroll
    for (int i = 0; i < 8; i++) {
        int f = t + i * 256;  // 0..2047
        int k = f >> 4, nq = f & 15;
        float4 v = *(const float4*)(W + (size_t)k * N + n0 + nq * 4);
        Tl[k][nq * 4 + 0] = v.x; Tl[k][nq * 4 + 1] = v.y;
        Tl[k][nq * 4 + 2] = v.z; Tl[k][nq * 4 + 3] = v.w;
    }
    __syncthreads();
    int nl = t >> 2, kq = t & 3;  // col n0+nl, k-range kq*32..+31
    unsigned hi[16], lo[16];
    #pragma unroll
    for (int d = 0; d < 16; d++) {
        float x0 = Tl[kq * 32 + 2 * d][nl];
        float x1 = Tl[kq * 32 + 2 * d + 1][nl];
        split2(x0, x1, hi[d], lo[d]);
    }
    size_t col = n0 + nl;
    uint4* H = (uint4*)Oh + col * 16 + kq * 4;
    uint4* L = (uint4*)Ol + col * 16 + kq * 4;
    #pragma unroll
    for (int j = 0; j < 4; j++) {
        H[j] = make_uint4(hi[4 * j], hi[4 * j + 1], hi[4 * j + 2], hi[4 * j + 3]);
        L[j] = make_uint4(lo[4 * j], lo[4 * j + 1], lo[4 * j + 2], lo[4 * j + 3]);
    }
}

// ---------------------------------------------------------------------------
// CSR build.
// ---------------------------------------------------------------------------
__global__ __launch_bounds__(256) void k_count(const int* __restrict__ dst,
                                               int* __restrict__ counts) {
    int e = blockIdx.x * 256 + threadIdx.x;
    if (e < N_EDGES) {
        unsigned d = (unsigned)dst[e];
        if (d < N_NODES) atomicAdd(&counts[d], 1);
    }
}

__global__ __launch_bounds__(1024) void k_scan(const int* __restrict__ counts,
                                               int* __restrict__ offs) {
    __shared__ int part[1024];
    int tid = threadIdx.x;
    const int chunk = (N_NODES + 1023) / 1024;
    int lo = tid * chunk;
    int hi = min(lo + chunk, N_NODES);
    int s = 0;
    for (int i = lo; i < hi; i++) s += counts[i];
    part[tid] = s;
    __syncthreads();
    for (int off = 1; off < 1024; off <<= 1) {
        int v = (tid >= off) ? part[tid - off] : 0;
        __syncthreads();
        part[tid] += v;
        __syncthreads();
    }
    int run = part[tid] - s;
    for (int i = lo; i < hi; i++) { offs[i] = run; run += counts[i]; }
    if (lo < N_NODES && hi == N_NODES) offs[N_NODES] = run;
}

__global__ __launch_bounds__(256) void k_fill(const int* __restrict__ src,
                                              const int* __restrict__ dst,
                                              const int* __restrict__ offs,
                                              int* __restrict__ cursor,
                                              int* __restrict__ csr) {
    int e = blockIdx.x * 256 + threadIdx.x;
    if (e < N_EDGES) {
        unsigned d = (unsigned)dst[e];
        unsigned s = (unsigned)src[e];
        if (d < N_NODES && s < N_NODES) {
            int p = atomicAdd(&cursor[d], 1);
            csr[offs[d] + p] = (int)s;
        }
    }
}

// ---------------------------------------------------------------------------
// Aggregation: agg[i] = feats[i] + sum_{e: dst==i} feats[src_e]
// ---------------------------------------------------------------------------
__global__ __launch_bounds__(256) void k_agg(const float* __restrict__ feats,
                                             float* __restrict__ agg,
                                             const int* __restrict__ offs,
                                             const int* __restrict__ csr) {
    int node = blockIdx.x * 4 + (threadIdx.x >> 6);
    int lane = threadIdx.x & 63;
    const float2* f2 = (const float2*)feats;
    float2 acc = f2[node * 64 + lane];
    int j0 = offs[node], j1 = offs[node + 1];
    for (int j = j0; j < j1; j++) {
        int s = csr[j];
        float2 v = f2[s * 64 + lane];
        acc.x += v.x; acc.y += v.y;
    }
    ((float2*)agg)[node * 64 + lane] = acc;
}

// ---------------------------------------------------------------------------
// Hash layer via bf16x3 MFMA: h = relu(agg @ W + b) + fused BN column stats.
// Block: 64 rows x 128 cols, 4 waves (wave = 16 rows x 128 cols), 36 KB LDS.
// ---------------------------------------------------------------------------
__global__ __launch_bounds__(256) void k_hash_mfma(
    const float* __restrict__ Xagg,
    const unsigned* __restrict__ WhiT, const unsigned* __restrict__ WloT,
    const float* __restrict__ bias, float* __restrict__ h,
    float* __restrict__ stat_sum, float* __restrict__ stat_sq) {
    __shared__ unsigned short Ahi[64 * FEAT];   // 16 KB
    __shared__ unsigned short Alo[64 * FEAT];   // 16 KB
    __shared__ float colred[2][4][FEAT];        // 4 KB

    int t = threadIdx.x;
    int row0 = blockIdx.x * 64;
    stage_split<64, 256>(Xagg, row0, Ahi, Alo, t);
    __syncthreads();

    int wave = t >> 6, lane = t & 63;
    int g = lane >> 4, q = lane & 15;

    f32x4 acc[8];
    #pragma unroll
    for (int n = 0; n < 8; n++) acc[n] = (f32x4){0.f, 0.f, 0.f, 0.f};

    int arow = wave * 16 + q;
    const uint4* BH = (const uint4*)WhiT;
    const uint4* BL = (const uint4*)WloT;

    for (int s = 0; s < 4; s++) {
        int aoff = arow * 256 + (((s * 64) + (g * 16)) ^ ((arow & 7) << 4));
        bh8 ah = *(const bh8*)((const char*)Ahi + aoff);
        bh8 al = *(const bh8*)((const char*)Alo + aoff);
        #pragma unroll
        for (int n = 0; n < 8; n++) {
            int idx = (n * 16 + q) * 16 + s * 4 + g;  // [col][k] uint4 units
            bh8 bhf = __builtin_bit_cast(bh8, BH[idx]);
            bh8 blf = __builtin_bit_cast(bh8, BL[idx]);
            acc[n] = __builtin_amdgcn_mfma_f32_16x16x32_bf16(ah, bhf, acc[n], 0, 0, 0);
            acc[n] = __builtin_amdgcn_mfma_f32_16x16x32_bf16(ah, blf, acc[n], 0, 0, 0);
            acc[n] = __builtin_amdgcn_mfma_f32_16x16x32_bf16(al, bhf, acc[n], 0, 0, 0);
        }
    }

    // epilogue: bias + relu + mask, store h, column stats
    float vmask[4];
    #pragma unroll
    for (int j = 0; j < 4; j++)
        vmask[j] = (row0 + wave * 16 + g * 4 + j < N_NODES) ? 1.f : 0.f;
    #pragma unroll
    for (int n = 0; n < 8; n++) {
        int col = n * 16 + q;
        float b = bias[col];
        float cs = 0.f, cq = 0.f;
        #pragma unroll
        for (int j = 0; j < 4; j++) {
            float v = fmaxf(acc[n][j] + b, 0.f) * vmask[j];
            if (vmask[j] != 0.f)
                h[(size_t)(row0 + wave * 16 + g * 4 + j) * FEAT + col] = v;
            cs += v; cq += v * v;
        }
        cs += __shfl_xor(cs, 16); cs += __shfl_xor(cs, 32);
        cq += __shfl_xor(cq, 16); cq += __shfl_xor(cq, 32);
        if (g == 0) { colred[0][wave][col] = cs; colred[1][wave][col] = cq; }
    }
    __syncthreads();
    if (t < FEAT) {
        float s = 0.f, qq = 0.f;
        #pragma unroll
        for (int w2 = 0; w2 < 4; w2++) { s += colred[0][w2][t]; qq += colred[1][w2][t]; }
        atomicAdd(&stat_sum[t], s);
        atomicAdd(&stat_sq[t], qq);
    }
}

// ---------------------------------------------------------------------------
// BN finalize + apply.
// ---------------------------------------------------------------------------
__global__ void k_finalize(float* stat_sum, float* stat_sq,
                           const float* __restrict__ gamma,
                           const float* __restrict__ beta) {
    int c = threadIdx.x;
    float mu = stat_sum[c] * (1.f / N_NODES);
    float var = stat_sq[c] * (1.f / N_NODES) - mu * mu;
    float sc = gamma[c] * rsqrtf(var + BN_EPS);
    float sh = beta[c] - mu * sc;
    stat_sum[c] = sc;
    stat_sq[c] = sh;
}

__global__ __launch_bounds__(256) void k_bnapply(float* __restrict__ h,
                                                 const float* __restrict__ scale,
                                                 const float* __restrict__ shift) {
    int i = blockIdx.x * 256 + threadIdx.x;
    const float4* sc4 = (const float4*)scale;
    const float4* sh4 = (const float4*)shift;
    if (i < N_NODES * 32) {
        float4 v = ((float4*)h)[i];
        int cb = i & 31;
        float4 s = sc4[cb], b = sh4[cb];
        v.x = v.x * s.x + b.x;
        v.y = v.y * s.y + b.y;
        v.z = v.z * s.z + b.z;
        v.w = v.w * s.w + b.w;
        ((float4*)h)[i] = v;
    }
}

// ---------------------------------------------------------------------------
// Fused softmax-sum GEMM via bf16x3 MFMA.
// Block: 32 rows x 2048 cols, 8 waves = 2 rowgrp x 4 colgrp.
// Wave: 16 rows x 512 cols = 32 subtiles, acc 32 x f32x4 (128 VGPR).
// C layout (m89): col = lane&15 (+n*16+cg*512), row = (lane>>4)*4 + reg.
// ---------------------------------------------------------------------------
__global__ __launch_bounds__(512) void k_smgemm_mfma(
    const float* __restrict__ X,
    const unsigned* __restrict__ WhiT, const unsigned* __restrict__ WloT,
    const float* __restrict__ bias, float* __restrict__ fp) {
    __shared__ unsigned short Ahi[32 * FEAT];  // 8 KB
    __shared__ unsigned short Alo[32 * FEAT];  // 8 KB
    __shared__ float fpacc[FP_LEN];            // 8 KB
    __shared__ float red[32 * 4];

    int t = threadIdx.x;
    int row0 = blockIdx.x * 32;

    #pragma unroll
    for (int i = 0; i < 4; i++) fpacc[t + i * 512] = 0.f;

    stage_split<32, 512>(X, row0, Ahi, Alo, t);
    __syncthreads();

    int wave = t >> 6, lane = t & 63;
    int rg = wave >> 2, cg = wave & 3;
    int g = lane >> 4, q = lane & 15;

    f32x4 acc[32];
    #pragma unroll
    for (int n = 0; n < 32; n++) acc[n] = (f32x4){0.f, 0.f, 0.f, 0.f};

    int arow = rg * 16 + q;
    const uint4* BH = (const uint4*)WhiT;
    const uint4* BL = (const uint4*)WloT;
    int bbase = (cg * 512 + q) * 16 + g;  // [col][k] uint4 units; +n*256, +s*4

    for (int s = 0; s < 4; s++) {
        int aoff = arow * 256 + (((s * 64) + (g * 16)) ^ ((arow & 7) << 4));
        bh8 ah = *(const bh8*)((const char*)Ahi + aoff);
        bh8 al = *(const bh8*)((const char*)Alo + aoff);
        int base = bbase + s * 4;
        uint4 bh = BH[base], bl = BL[base];  // n=0 preload
        #pragma unroll
        for (int n = 0; n < 32; n++) {
            uint4 bhc = bh, blc = bl;
            if (n < 31) { bh = BH[base + (n + 1) * 256]; bl = BL[base + (n + 1) * 256]; }
            bh8 bhf = __builtin_bit_cast(bh8, bhc);
            bh8 blf = __builtin_bit_cast(bh8, blc);
            acc[n] = __builtin_amdgcn_mfma_f32_16x16x32_bf16(ah, bhf, acc[n], 0, 0, 0);
            acc[n] = __builtin_amdgcn_mfma_f32_16x16x32_bf16(ah, blf, acc[n], 0, 0, 0);
            acc[n] = __builtin_amdgcn_mfma_f32_16x16x32_bf16(al, bhf, acc[n], 0, 0, 0);
        }
    }

    // ---- softmax epilogue (logits fully in registers) ----
    int colb = cg * 512 + q;
    float m[4] = {-3.4e38f, -3.4e38f, -3.4e38f, -3.4e38f};
    #pragma unroll
    for (int n = 0; n < 32; n++) {
        float b = bias[colb + n * 16];
        #pragma unroll
        for (int j = 0; j < 4; j++) {
            acc[n][j] += b;
            m[j] = fmaxf(m[j], acc[n][j]);
        }
    }
    #pragma unroll
    for (int j = 0; j < 4; j++) {
        m[j] = fmaxf(m[j], __shfl_xor(m[j], 1));
        m[j] = fmaxf(m[j], __shfl_xor(m[j], 2));
        m[j] = fmaxf(m[j], __shfl_xor(m[j], 4));
        m[j] = fmaxf(m[j], __shfl_xor(m[j], 8));
    }
    if (q == 0) {
        #pragma unroll
        for (int j = 0; j < 4; j++) red[(rg * 16 + g * 4 + j) * 4 + cg] = m[j];
    }
    __syncthreads();
    #pragma unroll
    for (int j = 0; j < 4; j++) {
        const float* r = &red[(rg * 16 + g * 4 + j) * 4];
        m[j] = fmaxf(fmaxf(r[0], r[1]), fmaxf(r[2], r[3]));
    }
    __syncthreads();  // red reads done before sum-partial writes

    float sm[4] = {0.f, 0.f, 0.f, 0.f};
    #pragma unroll
    for (int n = 0; n < 32; n++)
        #pragma unroll
        for (int j = 0; j < 4; j++) {
            float e = __expf(acc[n][j] - m[j]);
            acc[n][j] = e;
            sm[j] += e;
        }
    #pragma unroll
    for (int j = 0; j < 4; j++) {
        sm[j] += __shfl_xor(sm[j], 1);
        sm[j] += __shfl_xor(sm[j], 2);
        sm[j] += __shfl_xor(sm[j], 4);
        sm[j] += __shfl_xor(sm[j], 8);
    }
    if (q == 0) {
        #pragma unroll
        for (int j = 0; j < 4; j++) red[(rg * 16 + g * 4 + j) * 4 + cg] = sm[j];
    }
    __syncthreads();
    float invZ[4];
    #pragma unroll
    for (int j = 0; j < 4; j++) {
        const float* r = &red[(rg * 16 + g * 4 + j) * 4];
        float Z = r[0] + r[1] + r[2] + r[3];
        float vm = (row0 + rg * 16 + g * 4 + j < N_NODES) ? 1.f : 0.f;
        invZ[j] = vm / Z;  // masks OOB rows out of the column sums
    }
    #pragma unroll
    for (int n = 0; n < 32; n++) {
        float c = acc[n][0] * invZ[0] + acc[n][1] * invZ[1] +
                  acc[n][2] * invZ[2] + acc[n][3] * invZ[3];
        c += __shfl_xor(c, 16);
        c += __shfl_xor(c, 32);
        if (g == 0) atomicAdd(&fpacc[colb + n * 16], c);
    }
    __syncthreads();
    #pragma unroll
    for (int i = 0; i < 4; i++) {
        int cidx = t + i * 512;
        atomicAdd(&fp[cidx], fpacc[cidx]);
    }
}

// ---------------------------------------------------------------------------
// Launch
// ---------------------------------------------------------------------------
extern "C" void kernel_launch(void* const* d_in, const int* in_sizes, int n_in,
                              void* d_out, int out_size, void* d_ws, size_t ws_size,
                              hipStream_t stream) {
    const float* atoms  = (const float*)d_in[0];
    const int*   eidx   = (const int*)d_in[1];
    const float* init_w = (const float*)d_in[2];
    const float* init_b = (const float*)d_in[3];
    const float* hash_w = (const float*)d_in[4];
    const float* hash_b = (const float*)d_in[5];
    const float* soft_w = (const float*)d_in[6];
    const float* soft_b = (const float*)d_in[7];
    const float* gamma  = (const float*)d_in[8];
    const float* beta   = (const float*)d_in[9];
    float* fp = (float*)d_out;

    char* ws = (char*)d_ws;
    float* F      = (float*)ws; ws += (size_t)N_NODES * FEAT * 4;
    float* A      = (float*)ws; ws += (size_t)N_NODES * FEAT * 4;
    int*   counts = (int*)ws;   ws += (size_t)N_NODES * 4;
    int*   cursor = (int*)ws;   ws += (size_t)N_NODES * 4;
    int*   offs   = (int*)ws;   ws += (size_t)(N_NODES + 4) * 4;
    int*   csr    = (int*)ws;   ws += (size_t)N_EDGES * 4;
    float* stats  = (float*)ws; ws += (size_t)RADIUS * 2 * FEAT * 4;
    unsigned* WhiB = (unsigned*)ws; ws += (size_t)5 * FP_LEN * (FEAT / 2) * 4;
    unsigned* WloB = (unsigned*)ws; ws += (size_t)5 * FP_LEN * (FEAT / 2) * 4;
    unsigned* WhiH = (unsigned*)ws; ws += (size_t)RADIUS * FEAT * (FEAT / 2) * 4;
    unsigned* WloH = (unsigned*)ws; ws += (size_t)RADIUS * FEAT * (FEAT / 2) * 4;

    const int* src = eidx;
    const int* dst = eidx + N_EDGES;

    k_zero<<<256, 256, 0, stream>>>(fp, stats, counts, cursor);
    k_wsplit<<<dim3(32, 9), 256, 0, stream>>>(init_w, soft_w, hash_w,
                                              WhiB, WloB, WhiH, WloH);
    k_count<<<(N_EDGES + 255) / 256, 256, 0, stream>>>(dst, counts);
    k_scan<<<1, 1024, 0, stream>>>(counts, offs);
    k_fill<<<(N_EDGES + 255) / 256, 256, 0, stream>>>(src, dst, offs, cursor, csr);

    const int SMG = (N_NODES + 31) / 32;    // 1563
    const int HG  = (N_NODES + 63) / 64;    // 782

    k_smgemm_mfma<<<SMG, 512, 0, stream>>>(atoms, WhiB, WloB, init_b, fp);

    const float* feats = atoms;
    for (int l = 0; l < RADIUS; l++) {
        k_agg<<<N_NODES / 4, 256, 0, stream>>>(feats, A, offs, csr);
        float* ss = stats + l * 2 * FEAT;
        float* sq = ss + FEAT;
        k_hash_mfma<<<HG, 256, 0, stream>>>(
            A, WhiH + (size_t)l * FEAT * (FEAT / 2),
            WloH + (size_t)l * FEAT * (FEAT / 2),
            hash_b + (size_t)l * FEAT, F, ss, sq);
        k_finalize<<<1, FEAT, 0, stream>>>(ss, sq, gamma, beta);
        k_bnapply<<<(N_NODES * 32 + 255) / 256, 256, 0, stream>>>(F, ss, sq);
        k_smgemm_mfma<<<SMG, 512, 0, stream>>>(
            F, WhiB + (size_t)(1 + l) * FP_LEN * (FEAT / 2),
            WloB + (size_t)(1 + l) * FP_LEN * (FEAT / 2),
            soft_b + (size_t)l * FP_LEN, fp);
        feats = F;
    }
}